// Round 1
// baseline (1398.961 us; speedup 1.0000x reference)
//
#include <hip/hip_runtime.h>

// ---------------------------------------------------------------------------
// MPNN forward, fp32.  msg@w1 decomposed into per-node p=h@w1a, q=h@w1b plus
// per-edge ea@w1c, so edge work = relu(p[tgt]+q[src]+ea@w1c+b1) @ w2 + b2,
// scatter-max via monotone-uint-encoded atomicMax.
// ---------------------------------------------------------------------------

#define INIT_ENC 0x007FFFFFu   // enc(-inf)

__device__ __forceinline__ unsigned enc(float f) {
    unsigned u = __float_as_uint(f);
    return (u & 0x80000000u) ? ~u : (u | 0x80000000u);
}
__device__ __forceinline__ float dec_or_zero(unsigned u) {
    if (u == INIT_ENC) return 0.f;  // no incoming edge -> 0 (isfinite rule)
    return (u & 0x80000000u) ? __uint_as_float(u & 0x7fffffffu)
                             : __uint_as_float(~u);
}

// ---------------------------------------------------------------------------
// Generic small GEMM: C[M][N] = op(A[M][64] @ W[64][N] + bias), K fixed = 64.
// ---------------------------------------------------------------------------
template<int N, int M_TILE, bool RELU, bool BIAS>
__global__ __launch_bounds__(256) void gemm_k64(
    const float* __restrict__ A, const float* __restrict__ W,
    const float* __restrict__ bias, float* __restrict__ C, int M)
{
    constexpr int K = 64;
    constexpr int TCOLS = N / 4;          // threads across columns (float4)
    constexpr int TROWS = 256 / TCOLS;
    constexpr int RPT = M_TILE / TROWS;   // rows per thread
    __shared__ __align__(16) float Ws[K * N];
    __shared__ __align__(16) float As[M_TILE * (K + 4)];

    const int t = threadIdx.x;
    const int m0 = blockIdx.x * M_TILE;

    for (int i = t; i < K * N; i += 256) Ws[i] = W[i];

    // A tile: float4 loads, 16 rows per pass
    for (int rr = 0; rr < M_TILE; rr += 16) {
        int r = rr + (t >> 4);
        int c4 = (t & 15) * 4;
        int row = m0 + r;
        float4 v = make_float4(0.f, 0.f, 0.f, 0.f);
        if (row < M) v = *(const float4*)&A[(size_t)row * K + c4];
        *(float4*)&As[r * (K + 4) + c4] = v;
    }
    __syncthreads();

    const int tc = t % TCOLS;
    const int tr = t / TCOLS;
    float4 acc[RPT];
    float4 bv = make_float4(0.f, 0.f, 0.f, 0.f);
    if (BIAS) {
        bv.x = bias[tc * 4 + 0]; bv.y = bias[tc * 4 + 1];
        bv.z = bias[tc * 4 + 2]; bv.w = bias[tc * 4 + 3];
    }
#pragma unroll
    for (int i = 0; i < RPT; ++i) acc[i] = bv;

#pragma unroll 8
    for (int k = 0; k < K; ++k) {
        float4 w = *(const float4*)&Ws[k * N + tc * 4];
#pragma unroll
        for (int i = 0; i < RPT; ++i) {
            float a = As[(tr + i * TROWS) * (K + 4) + k];
            acc[i].x = fmaf(a, w.x, acc[i].x);
            acc[i].y = fmaf(a, w.y, acc[i].y);
            acc[i].z = fmaf(a, w.z, acc[i].z);
            acc[i].w = fmaf(a, w.w, acc[i].w);
        }
    }
#pragma unroll
    for (int i = 0; i < RPT; ++i) {
        int row = m0 + tr + i * TROWS;
        if (row < M) {
            float4 o = acc[i];
            if (RELU) {
                o.x = fmaxf(o.x, 0.f); o.y = fmaxf(o.y, 0.f);
                o.z = fmaxf(o.z, 0.f); o.w = fmaxf(o.w, 0.f);
            }
            *(float4*)&C[(size_t)row * N + tc * 4] = o;
        }
    }
}

// ---------------------------------------------------------------------------
// init agg to enc(-inf) and zero the BN stat accumulators
// ---------------------------------------------------------------------------
__global__ __launch_bounds__(256) void init_agg(unsigned* __restrict__ agg,
                                                float* __restrict__ stats,
                                                int total)
{
    int idx = blockIdx.x * 256 + threadIdx.x;
    if (idx < total) agg[idx] = INIT_ENC;
    if (blockIdx.x == 0 && threadIdx.x < 128) stats[threadIdx.x] = 0.f;
}

// ---------------------------------------------------------------------------
// Edge MLP + scatter-max.  32 edges per 256-thread block.
//   t1[e][c] = relu(p[tgt][c] + q[src][c] + sum_j ea[e][j]*w1c[j][c] + b1[c])
//   m[e][c]  = sum_k t1[e][k]*w2[k][c] + b2[c]
//   atomicMax(agg[tgt[e]][c], enc(m))
// ---------------------------------------------------------------------------
__global__ __launch_bounds__(256) void edge_mlp(
    const float* __restrict__ p, const float* __restrict__ q,
    const float* __restrict__ ea,
    const int* __restrict__ srcIdx, const int* __restrict__ tgtIdx,
    const float* __restrict__ w1c, const float* __restrict__ b1,
    const float* __restrict__ w2, const float* __restrict__ b2,
    unsigned* __restrict__ agg, int E)
{
    constexpr int EPB = 32;
    __shared__ __align__(16) float w2s[64 * 64];
    __shared__ __align__(16) float w1cs[16 * 64];
    __shared__ float b1s[64], b2s[64];
    __shared__ __align__(16) float eas[EPB * 16];
    __shared__ float t1s[EPB * 68];          // stride 68 breaks bank conflicts
    __shared__ int tgts[EPB], srcs[EPB];

    const int t = threadIdx.x;
    const int e0 = blockIdx.x * EPB;

    for (int i = t; i < 64 * 64; i += 256) w2s[i] = w2[i];
    for (int i = t; i < 16 * 64; i += 256) w1cs[i] = w1c[i];
    if (t < 64) { b1s[t] = b1[t]; b2s[t] = b2[t]; }
    if (t < EPB) {
        int e = e0 + t;
        tgts[t] = (e < E) ? tgtIdx[e] : 0;
        srcs[t] = (e < E) ? srcIdx[e] : 0;
    }
    for (int i = t; i < EPB * 16; i += 256) {
        int e = e0 + (i >> 4);
        eas[i] = (e < E) ? ea[(size_t)e * 16 + (i & 15)] : 0.f;
    }
    __syncthreads();

    // ---- phase 1: t1 ----
    {
        const int c = t & 63;
        const int eg = t >> 6;      // 0..3
#pragma unroll
        for (int ei = eg; ei < EPB; ei += 4) {
            int e = e0 + ei;
            float v = 0.f;
            if (e < E) {
                v = p[(size_t)tgts[ei] * 64 + c] + q[(size_t)srcs[ei] * 64 + c] + b1s[c];
#pragma unroll
                for (int j = 0; j < 16; ++j)
                    v = fmaf(eas[ei * 16 + j], w1cs[j * 64 + c], v);
                v = fmaxf(v, 0.f);
            }
            t1s[ei * 68 + c] = v;
        }
    }
    __syncthreads();

    // ---- phase 2: m = t1 @ w2 + b2, scatter-max ----
    {
        const int cg = t & 15;       // 4 cols per thread
        const int ep = t >> 4;       // edges ep and ep+16
        const int c0 = cg * 4;
        float4 acc0, acc1;
        acc0.x = acc1.x = b2s[c0 + 0];
        acc0.y = acc1.y = b2s[c0 + 1];
        acc0.z = acc1.z = b2s[c0 + 2];
        acc0.w = acc1.w = b2s[c0 + 3];
#pragma unroll 8
        for (int k = 0; k < 64; ++k) {
            float4 w = *(const float4*)&w2s[k * 64 + c0];
            float ta = t1s[ep * 68 + k];
            float tb = t1s[(ep + 16) * 68 + k];
            acc0.x = fmaf(ta, w.x, acc0.x);
            acc0.y = fmaf(ta, w.y, acc0.y);
            acc0.z = fmaf(ta, w.z, acc0.z);
            acc0.w = fmaf(ta, w.w, acc0.w);
            acc1.x = fmaf(tb, w.x, acc1.x);
            acc1.y = fmaf(tb, w.y, acc1.y);
            acc1.z = fmaf(tb, w.z, acc1.z);
            acc1.w = fmaf(tb, w.w, acc1.w);
        }
        int e_a = e0 + ep, e_b = e0 + ep + 16;
        if (e_a < E) {
            unsigned* dst = agg + (size_t)tgts[ep] * 64 + c0;
            atomicMax(dst + 0, enc(acc0.x));
            atomicMax(dst + 1, enc(acc0.y));
            atomicMax(dst + 2, enc(acc0.z));
            atomicMax(dst + 3, enc(acc0.w));
        }
        if (e_b < E) {
            unsigned* dst = agg + (size_t)tgts[ep + 16] * 64 + c0;
            atomicMax(dst + 0, enc(acc1.x));
            atomicMax(dst + 1, enc(acc1.y));
            atomicMax(dst + 2, enc(acc1.z));
            atomicMax(dst + 3, enc(acc1.w));
        }
    }
}

// ---------------------------------------------------------------------------
// BN: column sums / sumsq  (64 channels)
// ---------------------------------------------------------------------------
__global__ __launch_bounds__(256) void bn_reduce(const unsigned* __restrict__ agg,
                                                 float* __restrict__ stats, int M)
{
    __shared__ float ss[4 * 64], ss2[4 * 64];
    const int c = threadIdx.x & 63;
    const int rg = threadIdx.x >> 6;
    float s = 0.f, s2 = 0.f;
    for (int r = blockIdx.x * 4 + rg; r < M; r += gridDim.x * 4) {
        float v = dec_or_zero(agg[(size_t)r * 64 + c]);
        s += v;
        s2 = fmaf(v, v, s2);
    }
    ss[rg * 64 + c] = s;
    ss2[rg * 64 + c] = s2;
    __syncthreads();
    if (threadIdx.x < 64) {
        float ts = ss[c] + ss[64 + c] + ss[128 + c] + ss[192 + c];
        float ts2 = ss2[c] + ss2[64 + c] + ss2[128 + c] + ss2[192 + c];
        atomicAdd(&stats[c], ts);
        atomicAdd(&stats[64 + c], ts2);
    }
}

// ---------------------------------------------------------------------------
// BN normalize + relu, in place (agg uint -> h float, same buffer)
// ---------------------------------------------------------------------------
__global__ __launch_bounds__(256) void bn_norm(unsigned* __restrict__ hagg,
    const float* __restrict__ stats, const float* __restrict__ gamma,
    const float* __restrict__ beta, int M)
{
    int idx = blockIdx.x * 256 + threadIdx.x;
    if (idx >= M * 64) return;
    int c = idx & 63;
    float inv = 1.f / (float)M;
    float mu = stats[c] * inv;
    float var = fmaxf(stats[64 + c] * inv - mu * mu, 0.f);
    float v = dec_or_zero(hagg[idx]);
    float o = gamma[c] * (v - mu) * rsqrtf(var + 1e-5f) + beta[c];
    ((float*)hagg)[idx] = fmaxf(o, 0.f);
}

// ---------------------------------------------------------------------------
extern "C" void kernel_launch(void* const* d_in, const int* in_sizes, int n_in,
                              void* d_out, int out_size, void* d_ws, size_t ws_size,
                              hipStream_t stream)
{
    const float* x     = (const float*)d_in[0];
    const int*   eidx  = (const int*)  d_in[1];
    const float* ea    = (const float*)d_in[2];
    const float* w_in  = (const float*)d_in[3];
    const float* b_in  = (const float*)d_in[4];
    const float* w1    = (const float*)d_in[5];
    const float* b1    = (const float*)d_in[6];
    const float* w2    = (const float*)d_in[7];
    const float* b2    = (const float*)d_in[8];
    const float* gamma = (const float*)d_in[9];
    const float* beta  = (const float*)d_in[10];
    const float* w_m1  = (const float*)d_in[11];
    const float* b_m1  = (const float*)d_in[12];
    const float* w_m2  = (const float*)d_in[13];
    const float* b_m2  = (const float*)d_in[14];

    const int M = in_sizes[0] / 64;   // n_nodes
    const int E = in_sizes[1] / 2;    // n_edges
    const int* src = eidx;            // edge_index[0] = source
    const int* tgt = eidx + E;        // edge_index[1] = target (aggregation)

    // workspace layout (floats): hagg | p | q | stats  (~38.4 MB)
    float* hagg  = (float*)d_ws;
    float* pbuf  = hagg + (size_t)M * 64;
    float* qbuf  = pbuf + (size_t)M * 64;
    float* stats = qbuf + (size_t)M * 64;

    dim3 blk(256);
    const int gm64 = (M + 63) / 64;
    const int gelem = (M * 64 + 255) / 256;

    // h0 = relu(x @ w_in + b_in)
    gemm_k64<64, 64, true, true><<<gm64, blk, 0, stream>>>(x, w_in, b_in, hagg, M);

    for (int l = 0; l < 2; ++l) {
        const float* w1l = w1 + (size_t)l * 144 * 64;
        // p = h @ w1[0:64],  q = h @ w1[64:128]   (b1 added in edge kernel)
        gemm_k64<64, 64, false, false><<<gm64, blk, 0, stream>>>(hagg, w1l, nullptr, pbuf, M);
        gemm_k64<64, 64, false, false><<<gm64, blk, 0, stream>>>(hagg, w1l + 64 * 64, nullptr, qbuf, M);
        init_agg<<<gelem, blk, 0, stream>>>((unsigned*)hagg, stats, M * 64);
        edge_mlp<<<(E + 31) / 32, blk, 0, stream>>>(pbuf, qbuf, ea, src, tgt,
            w1l + 128 * 64, b1 + l * 64, w2 + (size_t)l * 64 * 64, b2 + l * 64,
            (unsigned*)hagg, E);
        bn_reduce<<<256, blk, 0, stream>>>((const unsigned*)hagg, stats, M);
        bn_norm<<<gelem, blk, 0, stream>>>((unsigned*)hagg, stats,
            gamma + l * 64, beta + l * 64, M);
    }

    // out = relu(h @ w_m1 + b_m1) @ w_m2 + b_m2
    gemm_k64<64, 64, true, true><<<gm64, blk, 0, stream>>>(hagg, w_m1, b_m1, pbuf, M);
    gemm_k64<32, 64, false, true><<<gm64, blk, 0, stream>>>(pbuf, w_m2, b_m2, (float*)d_out, M);
}

// Round 2
// 1319.115 us; speedup vs baseline: 1.0605x; 1.0605x over previous
//
#include <hip/hip_runtime.h>
#include <float.h>

// ---------------------------------------------------------------------------
// MPNN forward, fp32, CSR-grouped aggregation (no global atomics for max).
//   msg@w1 decomposed: per-node p=h@w1a, q=h@w1b; per-edge ea@w1c.
//   CSR (by target) built per call: hist -> scan -> fill(perm).
//   node_agg: block owns 8 nodes; edge MLP + LDS segmented max + BN stats.
// ---------------------------------------------------------------------------

__device__ __forceinline__ unsigned enc(float f) {
    unsigned u = __float_as_uint(f);
    return (u & 0x80000000u) ? ~u : (u | 0x80000000u);
}
__device__ __forceinline__ float dec(unsigned u) {
    return (u & 0x80000000u) ? __uint_as_float(u & 0x7fffffffu)
                             : __uint_as_float(~u);
}

// ---------------------------------------------------------------------------
// Generic small GEMM: C[M][N] = op(A[M][64] @ W[64][N] + bias), K fixed = 64.
// ---------------------------------------------------------------------------
template<int N, int M_TILE, bool RELU, bool BIAS>
__global__ __launch_bounds__(256) void gemm_k64(
    const float* __restrict__ A, const float* __restrict__ W,
    const float* __restrict__ bias, float* __restrict__ C, int M)
{
    constexpr int K = 64;
    constexpr int TCOLS = N / 4;
    constexpr int TROWS = 256 / TCOLS;
    constexpr int RPT = M_TILE / TROWS;
    __shared__ __align__(16) float Ws[K * N];
    __shared__ __align__(16) float As[M_TILE * (K + 4)];

    const int t = threadIdx.x;
    const int m0 = blockIdx.x * M_TILE;

    for (int i = t; i < K * N; i += 256) Ws[i] = W[i];

    for (int rr = 0; rr < M_TILE; rr += 16) {
        int r = rr + (t >> 4);
        int c4 = (t & 15) * 4;
        int row = m0 + r;
        float4 v = make_float4(0.f, 0.f, 0.f, 0.f);
        if (row < M) v = *(const float4*)&A[(size_t)row * K + c4];
        *(float4*)&As[r * (K + 4) + c4] = v;
    }
    __syncthreads();

    const int tc = t % TCOLS;
    const int tr = t / TCOLS;
    float4 acc[RPT];
    float4 bv = make_float4(0.f, 0.f, 0.f, 0.f);
    if (BIAS) {
        bv.x = bias[tc * 4 + 0]; bv.y = bias[tc * 4 + 1];
        bv.z = bias[tc * 4 + 2]; bv.w = bias[tc * 4 + 3];
    }
#pragma unroll
    for (int i = 0; i < RPT; ++i) acc[i] = bv;

#pragma unroll 8
    for (int k = 0; k < K; ++k) {
        float4 w = *(const float4*)&Ws[k * N + tc * 4];
#pragma unroll
        for (int i = 0; i < RPT; ++i) {
            float a = As[(tr + i * TROWS) * (K + 4) + k];
            acc[i].x = fmaf(a, w.x, acc[i].x);
            acc[i].y = fmaf(a, w.y, acc[i].y);
            acc[i].z = fmaf(a, w.z, acc[i].z);
            acc[i].w = fmaf(a, w.w, acc[i].w);
        }
    }
#pragma unroll
    for (int i = 0; i < RPT; ++i) {
        int row = m0 + tr + i * TROWS;
        if (row < M) {
            float4 o = acc[i];
            if (RELU) {
                o.x = fmaxf(o.x, 0.f); o.y = fmaxf(o.y, 0.f);
                o.z = fmaxf(o.z, 0.f); o.w = fmaxf(o.w, 0.f);
            }
            *(float4*)&C[(size_t)row * N + tc * 4] = o;
        }
    }
}

// ---------------------------------------------------------------------------
// CSR build
// ---------------------------------------------------------------------------
__global__ __launch_bounds__(256) void zero_cs(int* __restrict__ cnt,
                                               float* __restrict__ stats, int M)
{
    int i = blockIdx.x * 256 + threadIdx.x;
    if (i < M) cnt[i] = 0;
    if (blockIdx.x == 0) stats[threadIdx.x] = 0.f;   // 256 floats (2 layers)
}

__global__ __launch_bounds__(256) void hist_tgt(const int* __restrict__ tgt,
                                                int* __restrict__ cnt, int E)
{
    int e = blockIdx.x * 256 + threadIdx.x;
    if (e < E) atomicAdd(&cnt[tgt[e]], 1);
}

// single-block in-place exclusive scan of cnt[0..M)
__global__ __launch_bounds__(1024) void scan_counts(int* __restrict__ cnt, int M)
{
    __shared__ int part[1024];
    const int t = threadIdx.x;
    const int chunk = (M + 1023) / 1024;
    const int b = t * chunk;
    const int e = min(b + chunk, M);
    int s = 0;
    for (int i = b; i < e; ++i) s += cnt[i];
    part[t] = s;
    __syncthreads();
    for (int off = 1; off < 1024; off <<= 1) {
        int add = (t >= off) ? part[t - off] : 0;
        __syncthreads();
        part[t] += add;
        __syncthreads();
    }
    int run = (t > 0) ? part[t - 1] : 0;   // exclusive prefix
    for (int i = b; i < e; ++i) {
        int v = cnt[i];
        cnt[i] = run;
        run += v;
    }
}

// fill: perm[pos]=e, srcp[pos]=src[e].  After this, arr[n] == end of node n.
__global__ __launch_bounds__(256) void fill_csr(const int* __restrict__ tgt,
    const int* __restrict__ src, int* __restrict__ arr,
    int* __restrict__ perm, int* __restrict__ srcp, int E)
{
    int e = blockIdx.x * 256 + threadIdx.x;
    if (e < E) {
        int pos = atomicAdd(&arr[tgt[e]], 1);
        perm[pos] = e;
        srcp[pos] = src[e];
    }
}

// ---------------------------------------------------------------------------
// Fused per-node edge-MLP + segmented max + BN stats.
//   block owns NPB=8 consecutive nodes; edges tiled ET=120 at a time.
//   t1[e][c] = relu(p[tgt]+b1 + q[src] + ea@w1c)   (p[tgt] block-local)
//   m = t1 @ w2 + b2 ; max per node via LDS ds_max_u32 on encoded floats.
// ---------------------------------------------------------------------------
#define NPB 8
#define ET  120
#define TS  67    // t1 LDS stride: gcd(4*67,32)=4 -> 4-way worst on tv reads

__global__ __launch_bounds__(256, 2) void node_agg(
    const float* __restrict__ p, const float* __restrict__ q,
    const float* __restrict__ ea,
    const int* __restrict__ ends, const int* __restrict__ perm,
    const int* __restrict__ srcp,
    const float* __restrict__ w1c, const float* __restrict__ b1,
    const float* __restrict__ w2, const float* __restrict__ b2,
    float* __restrict__ hout, float* __restrict__ stats, int M)
{
    __shared__ __align__(16) float w2s[64 * 64];     // 16 KB
    __shared__ __align__(16) float w1cs[16 * 64];    // 4 KB
    __shared__ __align__(16) float t1s[ET * TS];     // 31.4 KB
    __shared__ __align__(16) float eas[ET * 16];     // 7.5 KB
    __shared__ __align__(16) float ps[NPB * 64];     // 2 KB
    __shared__ __align__(16) unsigned rmu[NPB * TS]; // 2.1 KB
    __shared__ __align__(16) float b2s[64];
    __shared__ __align__(16) int sidx[ET];
    __shared__ int endsL[NPB + 1];
    __shared__ unsigned char lnod[ET];

    const int t = threadIdx.x;
    const int n0 = blockIdx.x * NPB;

    for (int i = t; i < 64 * 64; i += 256) w2s[i] = w2[i];
    for (int i = t; i < 16 * 64; i += 256) w1cs[i] = w1c[i];
    if (t < 64) b2s[t] = b2[t];
    if (t <= NPB) {
        int n = n0 + t - 1;
        endsL[t] = (t == 0) ? ((n0 == 0) ? 0 : ends[n0 - 1])
                            : ((n < M) ? ends[n] : ends[M - 1]);
    }
    {
        int c = t & 63;
        for (int nn = t >> 6; nn < NPB; nn += 4) {
            int node = n0 + nn;
            ps[nn * 64 + c] = ((node < M) ? p[(size_t)node * 64 + c] : 0.f) + b1[c];
        }
    }
    for (int i = t; i < NPB * TS; i += 256) rmu[i] = 0u;   // 0 < enc(anything)
    __syncthreads();

    const int eBeg = endsL[0], eEnd = endsL[NPB];

    for (int tile = eBeg; tile < eEnd; tile += ET) {
        const int cnt = min(ET, eEnd - tile);

        // metadata + ea staging
        for (int i = t; i < ET; i += 256) {
            if (i < cnt) {
                int gp = tile + i;
                sidx[i] = srcp[gp];
                int L = 0;
                while (gp >= endsL[L + 1]) ++L;
                lnod[i] = (unsigned char)L;
            } else { sidx[i] = 0; lnod[i] = 0; }
        }
        for (int i = t; i < ET * 16; i += 256) {
            int ei = i >> 4;
            float v = 0.f;
            if (ei < cnt) {
                int pe = perm[tile + ei];
                v = ea[(size_t)pe * 16 + (i & 15)];
            }
            eas[i] = v;
        }
        __syncthreads();

        // phase 1: t1
        {
            const int c = t & 63;
            for (int i = t >> 6; i < ET; i += 4) {
                float v = 0.f;
                if (i < cnt) {
                    v = ps[lnod[i] * 64 + c] + q[(size_t)sidx[i] * 64 + c];
#pragma unroll
                    for (int j = 0; j < 16; ++j)
                        v = fmaf(eas[i * 16 + j], w1cs[j * 64 + c], v);
                    v = fmaxf(v, 0.f);
                }
                t1s[i * TS + c] = v;
            }
        }
        __syncthreads();

        // phase 2: m = t1 @ w2 + b2, seg-max into rmu
        {
            const int cg = t >> 5;          // 0..7  (8 cols each)
            const int eg = t & 31;          // 0..31 (4 edges each)
            const int c0 = cg * 8;
            const int e0 = eg * 4;
            if (e0 < cnt) {
                float acc[4][8];
#pragma unroll
                for (int e = 0; e < 4; ++e)
#pragma unroll
                    for (int j = 0; j < 8; ++j) acc[e][j] = b2s[c0 + j];

#pragma unroll 8
                for (int k = 0; k < 64; ++k) {
                    const float4 wa = *(const float4*)&w2s[k * 64 + c0];
                    const float4 wb = *(const float4*)&w2s[k * 64 + c0 + 4];
#pragma unroll
                    for (int e = 0; e < 4; ++e) {
                        const float tv = t1s[(e0 + e) * TS + k];
                        acc[e][0] = fmaf(tv, wa.x, acc[e][0]);
                        acc[e][1] = fmaf(tv, wa.y, acc[e][1]);
                        acc[e][2] = fmaf(tv, wa.z, acc[e][2]);
                        acc[e][3] = fmaf(tv, wa.w, acc[e][3]);
                        acc[e][4] = fmaf(tv, wb.x, acc[e][4]);
                        acc[e][5] = fmaf(tv, wb.y, acc[e][5]);
                        acc[e][6] = fmaf(tv, wb.z, acc[e][6]);
                        acc[e][7] = fmaf(tv, wb.w, acc[e][7]);
                    }
                }
                // segmented max, register pre-merge of same-node runs
                int curL = -1;
                float best[8];
#pragma unroll
                for (int e = 0; e < 4; ++e) {
                    int ge = e0 + e;
                    if (ge < cnt) {
                        int L = lnod[ge];
                        if (L != curL) {
                            if (curL >= 0) {
#pragma unroll
                                for (int j = 0; j < 8; ++j)
                                    atomicMax(&rmu[curL * TS + c0 + j], enc(best[j]));
                            }
                            curL = L;
#pragma unroll
                            for (int j = 0; j < 8; ++j) best[j] = acc[e][j];
                        } else {
#pragma unroll
                            for (int j = 0; j < 8; ++j) best[j] = fmaxf(best[j], acc[e][j]);
                        }
                    }
                }
                if (curL >= 0) {
#pragma unroll
                    for (int j = 0; j < 8; ++j)
                        atomicMax(&rmu[curL * TS + c0 + j], enc(best[j]));
                }
            }
        }
        __syncthreads();
    }

    // final store + BN stats.  (L,c) pairs: thread handles idx t and t+256.
#pragma unroll
    for (int pidx = 0; pidx < 2; ++pidx) {
        int idx = t + pidx * 256;
        int L = idx >> 6, c = idx & 63;
        int node = n0 + L;
        float v = 0.f;
        if (node < M) {
            if (endsL[L + 1] > endsL[L]) v = dec(rmu[L * TS + c]);
            hout[(size_t)node * 64 + c] = v;
        }
        ((float*)rmu)[L * TS + c] = v;   // own slot: no race
    }
    __syncthreads();
    if (t < 64) {
        float s = 0.f, s2 = 0.f;
#pragma unroll
        for (int L = 0; L < NPB; ++L) {
            float v = ((float*)rmu)[L * TS + t];
            s += v;
            s2 = fmaf(v, v, s2);
        }
        atomicAdd(&stats[t], s);
        atomicAdd(&stats[64 + t], s2);
    }
}

// ---------------------------------------------------------------------------
// BN normalize + relu, in place (plain float now)
// ---------------------------------------------------------------------------
__global__ __launch_bounds__(256) void bn_norm(float* __restrict__ h,
    const float* __restrict__ stats, const float* __restrict__ gamma,
    const float* __restrict__ beta, int M)
{
    int idx = blockIdx.x * 256 + threadIdx.x;
    if (idx >= M * 64) return;
    int c = idx & 63;
    float inv = 1.f / (float)M;
    float mu = stats[c] * inv;
    float var = fmaxf(stats[64 + c] * inv - mu * mu, 0.f);
    float v = h[idx];
    h[idx] = fmaxf(gamma[c] * (v - mu) * rsqrtf(var + 1e-5f) + beta[c], 0.f);
}

// ---------------------------------------------------------------------------
extern "C" void kernel_launch(void* const* d_in, const int* in_sizes, int n_in,
                              void* d_out, int out_size, void* d_ws, size_t ws_size,
                              hipStream_t stream)
{
    const float* x     = (const float*)d_in[0];
    const int*   eidx  = (const int*)  d_in[1];
    const float* ea    = (const float*)d_in[2];
    const float* w_in  = (const float*)d_in[3];
    const float* b_in  = (const float*)d_in[4];
    const float* w1    = (const float*)d_in[5];
    const float* b1    = (const float*)d_in[6];
    const float* w2    = (const float*)d_in[7];
    const float* b2    = (const float*)d_in[8];
    const float* gamma = (const float*)d_in[9];
    const float* beta  = (const float*)d_in[10];
    const float* w_m1  = (const float*)d_in[11];
    const float* b_m1  = (const float*)d_in[12];
    const float* w_m2  = (const float*)d_in[13];
    const float* b_m2  = (const float*)d_in[14];

    const int M = in_sizes[0] / 64;   // n_nodes
    const int E = in_sizes[1] / 2;    // n_edges
    const int* src = eidx;            // edge_index[0]
    const int* tgt = eidx + E;        // edge_index[1] (aggregation target)

    // ws: hagg | p | q | ends(M ints) | stats(256)       ~38.6 MB
    float* hagg  = (float*)d_ws;
    float* pbuf  = hagg + (size_t)M * 64;
    float* qbuf  = pbuf + (size_t)M * 64;
    int*   ends  = (int*)(qbuf + (size_t)M * 64);
    float* stats = (float*)(ends + M);
    // perm/srcp live in d_out (6.4 MB) — last used before head GEMMs write it
    int* perm = (int*)d_out;
    int* srcp = perm + E;

    dim3 blk(256);
    const int gm64  = (M + 63) / 64;
    const int gelem = (M * 64 + 255) / 256;
    const int gM    = (M + 255) / 256;
    const int gE    = (E + 255) / 256;

    // CSR build (used by both layers; tgt is layer-invariant)
    zero_cs<<<gM, blk, 0, stream>>>(ends, stats, M);
    hist_tgt<<<gE, blk, 0, stream>>>(tgt, ends, E);
    scan_counts<<<1, 1024, 0, stream>>>(ends, M);
    fill_csr<<<gE, blk, 0, stream>>>(tgt, src, ends, perm, srcp, E);

    // h0 = relu(x @ w_in + b_in)
    gemm_k64<64, 64, true, true><<<gm64, blk, 0, stream>>>(x, w_in, b_in, hagg, M);

    for (int l = 0; l < 2; ++l) {
        const float* w1l = w1 + (size_t)l * 144 * 64;
        gemm_k64<64, 64, false, false><<<gm64, blk, 0, stream>>>(hagg, w1l, nullptr, pbuf, M);
        gemm_k64<64, 64, false, false><<<gm64, blk, 0, stream>>>(hagg, w1l + 64 * 64, nullptr, qbuf, M);
        node_agg<<<(M + NPB - 1) / NPB, blk, 0, stream>>>(pbuf, qbuf, ea,
            ends, perm, srcp,
            w1l + 128 * 64, b1 + l * 64, w2 + (size_t)l * 64 * 64, b2 + l * 64,
            hagg, stats + l * 128, M);
        bn_norm<<<gelem, blk, 0, stream>>>(hagg, stats + l * 128,
            gamma + l * 64, beta + l * 64, M);
    }

    // out = relu(h @ w_m1 + b_m1) @ w_m2 + b_m2
    gemm_k64<64, 64, true, true><<<gm64, blk, 0, stream>>>(hagg, w_m1, b_m1, pbuf, M);
    gemm_k64<32, 64, false, true><<<gm64, blk, 0, stream>>>(pbuf, w_m2, b_m2, (float*)d_out, M);
}

// Round 4
// 811.008 us; speedup vs baseline: 1.7250x; 1.6265x over previous
//
#include <hip/hip_runtime.h>
#include <float.h>

// ---------------------------------------------------------------------------
// MPNN forward.  msg@w1 decomposed: per-node p=h@w1a, q=h@w1b (fused gemm_pq),
// per-edge ea@w1c fp32 VALU; edge GEMM t1@w2 via f16 MFMA 16x16x32;
// CSR-grouped blocks (8 nodes), LDS segmented max, BN stats fused.
//
// R4 fix: R3 overflowed d_ws (appended w2h past the R2-proven 38,601,024 B
// bound -> corrupted adjacent allocations -> calls 2+ used corrupted state).
// Now ws = hagg | pq | ends = 38,600,000 B; perm/w2h/stats live in d_out
// (all rebuilt each call before use; head GEMMs overwrite d_out last).
// ---------------------------------------------------------------------------

typedef _Float16 half8 __attribute__((ext_vector_type(8)));
typedef float floatx4 __attribute__((ext_vector_type(4)));

__device__ __forceinline__ unsigned enc(float f) {
    unsigned u = __float_as_uint(f);
    return (u & 0x80000000u) ? ~u : (u | 0x80000000u);
}
__device__ __forceinline__ float dec(unsigned u) {
    return (u & 0x80000000u) ? __uint_as_float(u & 0x7fffffffu)
                             : __uint_as_float(~u);
}

// ---------------------------------------------------------------------------
// Generic small GEMM: C[M][N] = op(A[M][64] @ W[64][N] + bias), K fixed = 64.
// ---------------------------------------------------------------------------
template<int N, int M_TILE, bool RELU, bool BIAS>
__global__ __launch_bounds__(256) void gemm_k64(
    const float* __restrict__ A, const float* __restrict__ W,
    const float* __restrict__ bias, float* __restrict__ C, int M)
{
    constexpr int K = 64;
    constexpr int TCOLS = N / 4;
    constexpr int TROWS = 256 / TCOLS;
    constexpr int RPT = M_TILE / TROWS;
    __shared__ __align__(16) float Ws[K * N];
    __shared__ __align__(16) float As[M_TILE * (K + 4)];

    const int t = threadIdx.x;
    const int m0 = blockIdx.x * M_TILE;

    for (int i = t; i < K * N; i += 256) Ws[i] = W[i];

    for (int rr = 0; rr < M_TILE; rr += 16) {
        int r = rr + (t >> 4);
        int c4 = (t & 15) * 4;
        int row = m0 + r;
        float4 v = make_float4(0.f, 0.f, 0.f, 0.f);
        if (row < M) v = *(const float4*)&A[(size_t)row * K + c4];
        *(float4*)&As[r * (K + 4) + c4] = v;
    }
    __syncthreads();

    const int tc = t % TCOLS;
    const int tr = t / TCOLS;
    float4 acc[RPT];
    float4 bv = make_float4(0.f, 0.f, 0.f, 0.f);
    if (BIAS) {
        bv.x = bias[tc * 4 + 0]; bv.y = bias[tc * 4 + 1];
        bv.z = bias[tc * 4 + 2]; bv.w = bias[tc * 4 + 3];
    }
#pragma unroll
    for (int i = 0; i < RPT; ++i) acc[i] = bv;

#pragma unroll 8
    for (int k = 0; k < K; ++k) {
        float4 w = *(const float4*)&Ws[k * N + tc * 4];
#pragma unroll
        for (int i = 0; i < RPT; ++i) {
            float a = As[(tr + i * TROWS) * (K + 4) + k];
            acc[i].x = fmaf(a, w.x, acc[i].x);
            acc[i].y = fmaf(a, w.y, acc[i].y);
            acc[i].z = fmaf(a, w.z, acc[i].z);
            acc[i].w = fmaf(a, w.w, acc[i].w);
        }
    }
#pragma unroll
    for (int i = 0; i < RPT; ++i) {
        int row = m0 + tr + i * TROWS;
        if (row < M) {
            float4 o = acc[i];
            if (RELU) {
                o.x = fmaxf(o.x, 0.f); o.y = fmaxf(o.y, 0.f);
                o.z = fmaxf(o.z, 0.f); o.w = fmaxf(o.w, 0.f);
            }
            *(float4*)&C[(size_t)row * N + tc * 4] = o;
        }
    }
}

// ---------------------------------------------------------------------------
// Fused p|q GEMM: PQ[M][128] = A[M][64] @ [w1a | w1b]   (w1 rows 0..127)
// ---------------------------------------------------------------------------
__global__ __launch_bounds__(256) void gemm_pq(
    const float* __restrict__ A, const float* __restrict__ W,
    float* __restrict__ PQ, int M)
{
    __shared__ __align__(16) float Ws[64 * 128];
    __shared__ __align__(16) float As[64 * 68];

    const int t = threadIdx.x;
    const int m0 = blockIdx.x * 64;

    for (int i = t; i < 64 * 128; i += 256) {
        int k = i >> 7, n = i & 127;
        Ws[i] = W[(size_t)((n < 64 ? k : 64 + k)) * 64 + (n & 63)];
    }
    for (int rr = 0; rr < 64; rr += 16) {
        int r = rr + (t >> 4);
        int c4 = (t & 15) * 4;
        int row = m0 + r;
        float4 v = make_float4(0.f, 0.f, 0.f, 0.f);
        if (row < M) v = *(const float4*)&A[(size_t)row * 64 + c4];
        *(float4*)&As[r * 68 + c4] = v;
    }
    __syncthreads();

    const int tc = t & 31;
    const int tr = t >> 5;
    float4 acc[8];
#pragma unroll
    for (int i = 0; i < 8; ++i) acc[i] = make_float4(0.f, 0.f, 0.f, 0.f);

#pragma unroll 8
    for (int k = 0; k < 64; ++k) {
        float4 w = *(const float4*)&Ws[k * 128 + tc * 4];
#pragma unroll
        for (int i = 0; i < 8; ++i) {
            float a = As[(tr + i * 8) * 68 + k];
            acc[i].x = fmaf(a, w.x, acc[i].x);
            acc[i].y = fmaf(a, w.y, acc[i].y);
            acc[i].z = fmaf(a, w.z, acc[i].z);
            acc[i].w = fmaf(a, w.w, acc[i].w);
        }
    }
#pragma unroll
    for (int i = 0; i < 8; ++i) {
        int row = m0 + tr + i * 8;
        if (row < M) *(float4*)&PQ[(size_t)row * 128 + tc * 4] = acc[i];
    }
}

// ---------------------------------------------------------------------------
// CSR build
// ---------------------------------------------------------------------------
__global__ __launch_bounds__(256) void zero_cs(int* __restrict__ cnt,
                                               float* __restrict__ stats, int M)
{
    int i = blockIdx.x * 256 + threadIdx.x;
    if (i < M) cnt[i] = 0;
    if (blockIdx.x == 0) stats[threadIdx.x] = 0.f;   // 256 floats (2 layers)
}

__global__ __launch_bounds__(256) void hist_tgt(const int* __restrict__ tgt,
                                                int* __restrict__ cnt, int E)
{
    int e = blockIdx.x * 256 + threadIdx.x;
    if (e < E) atomicAdd(&cnt[tgt[e]], 1);
}

__global__ __launch_bounds__(1024) void scan_counts(int* __restrict__ cnt, int M)
{
    __shared__ int part[1024];
    const int t = threadIdx.x;
    const int chunk = (M + 1023) / 1024;
    const int b = t * chunk;
    const int e = min(b + chunk, M);
    int s = 0;
    for (int i = b; i < e; ++i) s += cnt[i];
    part[t] = s;
    __syncthreads();
    for (int off = 1; off < 1024; off <<= 1) {
        int add = (t >= off) ? part[t - off] : 0;
        __syncthreads();
        part[t] += add;
        __syncthreads();
    }
    int run = (t > 0) ? part[t - 1] : 0;
    for (int i = b; i < e; ++i) {
        int v = cnt[i];
        cnt[i] = run;
        run += v;
    }
}

// fill: perm[pos]=e.  After this, arr[n] == end of node n.
__global__ __launch_bounds__(256) void fill_csr(const int* __restrict__ tgt,
    int* __restrict__ arr, int* __restrict__ perm, int E)
{
    int e = blockIdx.x * 256 + threadIdx.x;
    if (e < E) {
        int pos = atomicAdd(&arr[tgt[e]], 1);
        perm[pos] = e;
    }
}

// ---------------------------------------------------------------------------
// Pack w2 (both layers) into f16 MFMA B-fragment order:
//   w2h[l][ (nt*2+kc)*64 + lane ][j] = w2[l][ kc*32 + (lane>>4)*8 + j ][ nt*16 + (lane&15) ]
// ---------------------------------------------------------------------------
__global__ __launch_bounds__(256) void pack_w2(const float* __restrict__ w2,
                                               _Float16* __restrict__ w2h)
{
    int id = blockIdx.x * 256 + threadIdx.x;
    if (id >= 1024) return;
    int l = id >> 9, rem = id & 511;
    int frag = rem >> 6, lane = rem & 63;
    int nt = frag >> 1, kc = frag & 1;
    const float* W = w2 + (size_t)l * 4096;
    _Float16* O = w2h + (size_t)l * 4096 + (frag * 64 + lane) * 8;
    int n = nt * 16 + (lane & 15);
    int k0 = kc * 32 + (lane >> 4) * 8;
#pragma unroll
    for (int j = 0; j < 8; ++j) O[j] = (_Float16)W[(k0 + j) * 64 + n];
}

// ---------------------------------------------------------------------------
// Fused per-node edge-MLP + segmented max + BN stats.  MFMA phase 2.
// ---------------------------------------------------------------------------
#define NPB 8
#define ET  160
#define TSH 72    // t1 LDS row stride in halfs (144 B -> 2-way b128, free)

__global__ __launch_bounds__(256, 3) void node_agg(
    const float* __restrict__ pq, const float* __restrict__ ea,
    const int* __restrict__ srcG,
    const int* __restrict__ ends, const int* __restrict__ perm,
    const float* __restrict__ w1c, const float* __restrict__ b1,
    const _Float16* __restrict__ w2h, const float* __restrict__ b2,
    float* __restrict__ hout, float* __restrict__ stats, int M)
{
    __shared__ __align__(16) _Float16 t1h[ET * TSH];   // 23.0 KB
    __shared__ __align__(16) float eas[ET * 16];       // 10.2 KB
    __shared__ __align__(16) float w1cs[16 * 64];      //  4.0 KB
    __shared__ __align__(16) float ps[NPB * 64];       //  2.0 KB
    __shared__ __align__(16) unsigned rmu[NPB * 68];   //  2.2 KB
    __shared__ __align__(16) int sidx[ET];
    __shared__ __align__(16) int peS[ET];
    __shared__ int endsL[NPB + 1];
    __shared__ unsigned char lnodS[ET];

    const int t = threadIdx.x;
    const int lane = t & 63;
    const int wid = t >> 6;
    const int n0 = blockIdx.x * NPB;

    for (int i = t; i < 16 * 64; i += 256) w1cs[i] = w1c[i];
    if (t <= NPB) {
        int n = n0 + t - 1;
        endsL[t] = (t == 0) ? ((n0 == 0) ? 0 : ends[n0 - 1])
                            : ((n < M) ? ends[n] : ends[M - 1]);
    }
    {
        int c = t & 63;
        for (int nn = t >> 6; nn < NPB; nn += 4) {
            int node = n0 + nn;
            ps[nn * 64 + c] = ((node < M) ? pq[(size_t)node * 128 + c] : 0.f) + b1[c];
        }
    }
    for (int i = t; i < NPB * 68; i += 256) rmu[i] = 0u;   // 0 < enc(anything)

    // B fragments (w2), same for all waves
    half8 bfrag[4][2];
#pragma unroll
    for (int nt = 0; nt < 4; ++nt)
#pragma unroll
        for (int kc = 0; kc < 2; ++kc)
            bfrag[nt][kc] = *(const half8*)(w2h + ((nt * 2 + kc) * 64 + lane) * 8);

    __syncthreads();

    const int eBeg = endsL[0], eEnd = endsL[NPB];

    for (int tile = eBeg; tile < eEnd; tile += ET) {
        const int cnt = min(ET, eEnd - tile);

        // ---- stage metadata + edge_attr ----
        for (int i = t; i < ET; i += 256) {
            if (i < cnt) {
                int gp = tile + i;
                int pe = perm[gp];
                peS[i] = pe;
                sidx[i] = srcG[pe];
                int L = 0;
                while (gp >= endsL[L + 1]) ++L;
                lnodS[i] = (unsigned char)L;
            } else { peS[i] = 0; sidx[i] = 0; lnodS[i] = 0; }
        }
        __syncthreads();
        for (int i = t; i < ET * 16; i += 256) {
            int ei = i >> 4;
            float v = 0.f;
            if (ei < cnt) v = ea[(size_t)peS[ei] * 16 + (i & 15)];
            eas[i] = v;
        }
        __syncthreads();

        // ---- phase 1: t1 = relu(p[tgt]+b1 + q[src] + ea@w1c) -> f16 LDS ----
        {
            const int c = t & 63;
            for (int i = t >> 6; i < cnt; i += 4) {
                float v = ps[lnodS[i] * 64 + c] + pq[(size_t)sidx[i] * 128 + 64 + c];
#pragma unroll
                for (int j = 0; j < 16; ++j)
                    v = fmaf(eas[i * 16 + j], w1cs[j * 64 + c], v);
                t1h[i * TSH + c] = (_Float16)fmaxf(v, 0.f);
            }
        }
        __syncthreads();

        // ---- phase 2: m = t1 @ w2 via MFMA, segmented max into rmu ----
        {
            const int quad = lane >> 4;
            const int col = lane & 15;
            for (int mt = wid; mt * 16 < cnt; mt += 4) {
                const int e0 = mt * 16;
                floatx4 acc[4] = {{0.f,0.f,0.f,0.f},{0.f,0.f,0.f,0.f},
                                  {0.f,0.f,0.f,0.f},{0.f,0.f,0.f,0.f}};
#pragma unroll
                for (int kc = 0; kc < 2; ++kc) {
                    half8 a = *(const half8*)&t1h[(e0 + col) * TSH + kc * 32 + quad * 8];
#pragma unroll
                    for (int nt = 0; nt < 4; ++nt)
                        acc[nt] = __builtin_amdgcn_mfma_f32_16x16x32_f16(
                            a, bfrag[nt][kc], acc[nt], 0, 0, 0);
                }
                const int r0 = e0 + quad * 4;
#pragma unroll
                for (int nt = 0; nt < 4; ++nt) {
                    int curL = -1;
                    float best = 0.f;
#pragma unroll
                    for (int r = 0; r < 4; ++r) {
                        int ge = r0 + r;
                        if (ge < cnt) {
                            int L = lnodS[ge];
                            float v = acc[nt][r];
                            if (L != curL) {
                                if (curL >= 0)
                                    atomicMax(&rmu[curL * 68 + nt * 16 + col], enc(best));
                                curL = L; best = v;
                            } else best = fmaxf(best, v);
                        }
                    }
                    if (curL >= 0)
                        atomicMax(&rmu[curL * 68 + nt * 16 + col], enc(best));
                }
            }
        }
        __syncthreads();
    }

    // ---- final store (+b2) + BN stats ----
#pragma unroll
    for (int pidx = 0; pidx < 2; ++pidx) {
        int idx = t + pidx * 256;
        int L = idx >> 6, c = idx & 63;
        int node = n0 + L;
        float v = 0.f;
        if (node < M) {
            if (endsL[L + 1] > endsL[L]) v = dec(rmu[L * 68 + c]) + b2[c];
            hout[(size_t)node * 64 + c] = v;
        }
        ((float*)rmu)[L * 68 + c] = v;   // own slot: no race
    }
    __syncthreads();
    if (t < 64) {
        float s = 0.f, s2 = 0.f;
#pragma unroll
        for (int L = 0; L < NPB; ++L) {
            float v = ((float*)rmu)[L * 68 + t];
            s += v;
            s2 = fmaf(v, v, s2);
        }
        atomicAdd(&stats[t], s);
        atomicAdd(&stats[64 + t], s2);
    }
}

// ---------------------------------------------------------------------------
// BN normalize + relu, in place
// ---------------------------------------------------------------------------
__global__ __launch_bounds__(256) void bn_norm(float* __restrict__ h,
    const float* __restrict__ stats, const float* __restrict__ gamma,
    const float* __restrict__ beta, int M)
{
    int idx = blockIdx.x * 256 + threadIdx.x;
    if (idx >= M * 64) return;
    int c = idx & 63;
    float inv = 1.f / (float)M;
    float mu = stats[c] * inv;
    float var = fmaxf(stats[64 + c] * inv - mu * mu, 0.f);
    float v = h[idx];
    h[idx] = fmaxf(gamma[c] * (v - mu) * rsqrtf(var + 1e-5f) + beta[c], 0.f);
}

// ---------------------------------------------------------------------------
extern "C" void kernel_launch(void* const* d_in, const int* in_sizes, int n_in,
                              void* d_out, int out_size, void* d_ws, size_t ws_size,
                              hipStream_t stream)
{
    const float* x     = (const float*)d_in[0];
    const int*   eidx  = (const int*)  d_in[1];
    const float* ea    = (const float*)d_in[2];
    const float* w_in  = (const float*)d_in[3];
    const float* b_in  = (const float*)d_in[4];
    const float* w1    = (const float*)d_in[5];
    const float* b1    = (const float*)d_in[6];
    const float* w2    = (const float*)d_in[7];
    const float* b2    = (const float*)d_in[8];
    const float* gamma = (const float*)d_in[9];
    const float* beta  = (const float*)d_in[10];
    const float* w_m1  = (const float*)d_in[11];
    const float* b_m1  = (const float*)d_in[12];
    const float* w_m2  = (const float*)d_in[13];
    const float* b_m2  = (const float*)d_in[14];

    const int M = in_sizes[0] / 64;   // n_nodes
    const int E = in_sizes[1] / 2;    // n_edges
    const int* src = eidx;            // edge_index[0]
    const int* tgt = eidx + E;        // edge_index[1] (aggregation target)

    // ws: hagg[M*64] | pq[M*128] | ends[M]      = 38,600,000 B (< R2-proven 38,601,024)
    float* hagg  = (float*)d_ws;
    float* pqbuf = hagg + (size_t)M * 64;
    int*   ends  = (int*)(pqbuf + (size_t)M * 128);
    // d_out scratch: perm[E] | w2h[2*4096 halfs] | stats[256 floats]
    //   (3,217,408 B of 6,400,000; all rebuilt each call before use; head
    //    GEMMs overwrite d_out only after the last read of each)
    int* perm = (int*)d_out;
    _Float16* w2h = (_Float16*)((char*)d_out + (size_t)E * 4);
    float* stats  = (float*)((char*)d_out + (size_t)E * 4 + 2 * 4096 * 2);

    dim3 blk(256);
    const int gm64  = (M + 63) / 64;
    const int gelem = (M * 64 + 255) / 256;
    const int gM    = (M + 255) / 256;
    const int gE    = (E + 255) / 256;

    // CSR build + weight pack
    zero_cs<<<gM, blk, 0, stream>>>(ends, stats, M);
    hist_tgt<<<gE, blk, 0, stream>>>(tgt, ends, E);
    scan_counts<<<1, 1024, 0, stream>>>(ends, M);
    fill_csr<<<gE, blk, 0, stream>>>(tgt, ends, perm, E);
    pack_w2<<<4, blk, 0, stream>>>(w2, w2h);

    // h0 = relu(x @ w_in + b_in)
    gemm_k64<64, 64, true, true><<<gm64, blk, 0, stream>>>(x, w_in, b_in, hagg, M);

    for (int l = 0; l < 2; ++l) {
        const float* w1l = w1 + (size_t)l * 144 * 64;
        gemm_pq<<<gm64, blk, 0, stream>>>(hagg, w1l, pqbuf, M);
        node_agg<<<(M + NPB - 1) / NPB, blk, 0, stream>>>(pqbuf, ea, src,
            ends, perm,
            w1l + 128 * 64, b1 + l * 64, w2h + (size_t)l * 4096, b2 + l * 64,
            hagg, stats + l * 128, M);
        bn_norm<<<gelem, blk, 0, stream>>>(hagg, stats + l * 128,
            gamma + l * 64, beta + l * 64, M);
    }

    // out = relu(h @ w_m1 + b_m1) @ w_m2 + b_m2
    gemm_k64<64, 64, true, true><<<gm64, blk, 0, stream>>>(hagg, w_m1, b_m1, pqbuf, M);
    gemm_k64<32, 64, false, true><<<gm64, blk, 0, stream>>>(pqbuf, w_m2, b_m2, (float*)d_out, M);
}